// Round 4
// baseline (1492.475 us; speedup 1.0000x reference)
//
#include <hip/hip_runtime.h>
#include <hip/hip_bf16.h>

#define NN 100000
#define NE 800000
#define HIDDEN 128
#define NED (2 * NE)            // edge-directions: [0,NE)=fwd(by src), [NE,2NE)=bwd(by dst)
#define BKN 128                 // nodes per bucket
#define NBF 782                 // ceil(NN/BKN)
#define NBUCK (2 * NBF)         // 1564
#define CHUNK 16384
#define PBLK ((NED + CHUNK - 1) / CHUNK)   // 98

typedef __attribute__((ext_vector_type(8))) short bf16x8;
typedef __attribute__((ext_vector_type(4))) short bf16x4;
typedef __attribute__((ext_vector_type(4))) float f32x4;

__device__ __forceinline__ short f2bf(float f) {
  union { float f; unsigned u; } x; x.f = f;
  unsigned r = x.u + 0x7fffu + ((x.u >> 16) & 1u);   // RNE
  return (short)(r >> 16);
}

// ---- weights fp32 -> bf16 (order: [0]=Ws_w, [1]=W_w, [2]=Wt_w) ----
__global__ __launch_bounds__(256) void convert_weights(
    const float* __restrict__ m0, const float* __restrict__ m1,
    const float* __restrict__ m2, short* __restrict__ out) {
  int i = blockIdx.x * 256 + threadIdx.x;   // [0, 3*16384)
  int m = i >> 14, j = i & 16383;
  const float* s = (m == 0) ? m0 : (m == 1) ? m1 : m2;
  out[i] = f2bf(s[j]);
}

// ---- 1. global bucket histogram (LDS-aggregated; only 98*1564 global atomics) ----
__global__ __launch_bounds__(256) void part_count(
    const int* __restrict__ esrc, const int* __restrict__ edst,
    int* __restrict__ ghist) {
  __shared__ int lh[NBUCK];
  int tid = threadIdx.x;
  for (int i = tid; i < NBUCK; i += 256) lh[i] = 0;
  __syncthreads();
  int base = blockIdx.x * CHUNK;
  int nit = min(CHUNK, NED - base);
  for (int k = tid; k < nit; k += 256) {
    int ed = base + k;
    int b;
    if (ed < NE) b = esrc[ed] >> 7;
    else b = NBF + (edst[ed - NE] >> 7);
    atomicAdd(&lh[b], 1);
  }
  __syncthreads();
  for (int i = tid; i < NBUCK; i += 256) {
    int c = lh[i];
    if (c) atomicAdd(ghist + i, c);
  }
}

// ---- 2. exclusive scan over ghist[NBUCK] -> bstart (bounds) + gcur (cursors) ----
__global__ __launch_bounds__(1024) void bucket_scan(
    const int* __restrict__ ghist, int* __restrict__ bstart,
    int* __restrict__ gcur) {
  __shared__ int lds[1024];
  __shared__ int carry;
  int tid = threadIdx.x;
  if (tid == 0) carry = 0;
  __syncthreads();
  for (int t = 0; t < 2; t++) {
    int i = t * 1024 + tid;
    int v = (i < NBUCK) ? ghist[i] : 0;
    lds[tid] = v;
    __syncthreads();
    for (int off = 1; off < 1024; off <<= 1) {
      int x = lds[tid];
      int add = (tid >= off) ? lds[tid - off] : 0;
      __syncthreads();
      lds[tid] = x + add;
      __syncthreads();
    }
    int excl = lds[tid] - v + carry;
    if (i < NBUCK) { bstart[i] = excl; gcur[i] = excl; }
    int tot = lds[1023];
    __syncthreads();
    if (tid == 0) carry += tot;
    __syncthreads();
  }
  if (tid == 0) bstart[NBUCK] = carry;   // == NED
}

// ---- 3. radix partition: scatter through LDS, write coalesced runs to ELP ----
// ELP item: (tgt_local<<17) | nbr   (tgt_local<128 -> 7 bits; nbr<100000 -> 17 bits)
__global__ __launch_bounds__(256) void part_scatter(
    const int* __restrict__ esrc, const int* __restrict__ edst,
    int* __restrict__ gcur, unsigned* __restrict__ ELP) {
  __shared__ int lh[NBUCK];
  __shared__ int loff[NBUCK];     // block-local exclusive offsets (kept intact)
  __shared__ int lcur[NBUCK];     // mutable scatter cursors
  __shared__ int gbase[NBUCK];    // claimed global run starts
  __shared__ int psum[256];
  __shared__ unsigned buf[CHUNK]; // 64 KB staging
  int tid = threadIdx.x;
  for (int i = tid; i < NBUCK; i += 256) lh[i] = 0;
  __syncthreads();
  int base = blockIdx.x * CHUNK;
  int nit = min(CHUNK, NED - base);
  // pass 1: local count
  for (int k = tid; k < nit; k += 256) {
    int ed = base + k;
    int b;
    if (ed < NE) b = esrc[ed] >> 7;
    else b = NBF + (edst[ed - NE] >> 7);
    atomicAdd(&lh[b], 1);
  }
  __syncthreads();
  // local exclusive scan (7 buckets per thread; 7*256=1792 >= NBUCK)
  int s = 0;
  int lo0 = tid * 7, hi0 = min(NBUCK, tid * 7 + 7);
  for (int j = lo0; j < hi0; j++) s += lh[j];
  psum[tid] = s;
  __syncthreads();
  for (int off = 1; off < 256; off <<= 1) {
    int x = psum[tid];
    int add = (tid >= off) ? psum[tid - off] : 0;
    __syncthreads();
    psum[tid] = x + add;
    __syncthreads();
  }
  int run = psum[tid] - s;
  for (int j = lo0; j < hi0; j++) { loff[j] = run; lcur[j] = run; run += lh[j]; }
  __syncthreads();
  // claim global runs (one returning atomic per non-empty bucket)
  for (int b = tid; b < NBUCK; b += 256) {
    int c = lh[b];
    if (c) gbase[b] = atomicAdd(gcur + b, c);
  }
  __syncthreads();
  // pass 2: scatter into LDS staging
  for (int k = tid; k < nit; k += 256) {
    int ed = base + k;
    int b, tl, nbr;
    if (ed < NE) { int tg = esrc[ed]; nbr = edst[ed]; b = tg >> 7; tl = tg & 127; }
    else { int e = ed - NE; int tg = edst[e]; nbr = esrc[e]; b = NBF + (tg >> 7); tl = tg & 127; }
    int slot = atomicAdd(&lcur[b], 1);
    buf[slot] = ((unsigned)tl << 17) | (unsigned)nbr;
  }
  __syncthreads();
  // sweep: consecutive lanes -> consecutive slots -> bucket-contiguous global runs
  for (int i = tid; i < nit; i += 256) {
    int lo = 0, hi = NBUCK - 1;
    while (lo < hi) {                       // rightmost b with loff[b] <= i
      int mid = (lo + hi + 1) >> 1;
      if (loff[mid] <= i) lo = mid; else hi = mid - 1;
    }
    ELP[gbase[lo] + (i - loff[lo])] = buf[i];
  }
}

// ---- 4. bucket accumulate: 128-row fp32 LDS accumulator, ds_add_f32, no global RMW ----
__global__ __launch_bounds__(256) void bucket_accum(
    const float* __restrict__ h, const unsigned* __restrict__ ELP,
    const int* __restrict__ bstart,
    short* __restrict__ aggF, short* __restrict__ aggB,
    int* __restrict__ degFB) {
  __shared__ float acc[BKN * HIDDEN];   // 64 KB
  __shared__ int degL[BKN];
  int tid = threadIdx.x;
  for (int i = tid; i < BKN * HIDDEN; i += 256) acc[i] = 0.f;
  if (tid < BKN) degL[tid] = 0;
  __syncthreads();
  int blk = blockIdx.x;
  int s = bstart[blk], e = bstart[blk + 1];
  int hw = tid >> 5, q = tid & 31;      // half-wave per item; lane q -> banks q (conflict-free)
  int i = s + hw;
  for (; i + 8 < e; i += 16) {          // 2-way ILP
    unsigned pv0 = ELP[i], pv1 = ELP[i + 8];
    int n0 = pv0 & 0x1FFFF, t0 = pv0 >> 17;
    int n1 = pv1 & 0x1FFFF, t1 = pv1 >> 17;
    const float* r0 = h + (size_t)n0 * HIDDEN;
    const float* r1 = h + (size_t)n1 * HIDDEN;
    float a0 = r0[q], a1 = r0[q + 32], a2 = r0[q + 64], a3 = r0[q + 96];
    float b0 = r1[q], b1 = r1[q + 32], b2 = r1[q + 64], b3 = r1[q + 96];
    atomicAdd(&acc[t0 * HIDDEN + q], a0);
    atomicAdd(&acc[t0 * HIDDEN + q + 32], a1);
    atomicAdd(&acc[t0 * HIDDEN + q + 64], a2);
    atomicAdd(&acc[t0 * HIDDEN + q + 96], a3);
    atomicAdd(&acc[t1 * HIDDEN + q], b0);
    atomicAdd(&acc[t1 * HIDDEN + q + 32], b1);
    atomicAdd(&acc[t1 * HIDDEN + q + 64], b2);
    atomicAdd(&acc[t1 * HIDDEN + q + 96], b3);
    if (q == 0) { atomicAdd(&degL[t0], 1); atomicAdd(&degL[t1], 1); }
  }
  for (; i < e; i += 8) {
    unsigned pv = ELP[i];
    int n0 = pv & 0x1FFFF, t0 = pv >> 17;
    const float* r0 = h + (size_t)n0 * HIDDEN;
    float a0 = r0[q], a1 = r0[q + 32], a2 = r0[q + 64], a3 = r0[q + 96];
    atomicAdd(&acc[t0 * HIDDEN + q], a0);
    atomicAdd(&acc[t0 * HIDDEN + q + 32], a1);
    atomicAdd(&acc[t0 * HIDDEN + q + 64], a2);
    atomicAdd(&acc[t0 * HIDDEN + q + 96], a3);
    if (q == 0) atomicAdd(&degL[t0], 1);
  }
  __syncthreads();
  // coalesced bf16 write-out
  int dir = blk >= NBF;
  int node0 = (dir ? blk - NBF : blk) * BKN;
  short* agg = dir ? aggB : aggF;
  for (int u = tid; u < BKN * 32; u += 256) {
    int row = u >> 5, cg = u & 31;
    int node = node0 + row;
    if (node < NN) {
      bf16x4 o;
#pragma unroll
      for (int c = 0; c < 4; c++) o[c] = f2bf(acc[row * HIDDEN + cg * 4 + c]);
      *(bf16x4*)(agg + (size_t)node * HIDDEN + cg * 4) = o;
    }
  }
  if (tid < BKN) {
    int node = node0 + tid;
    if (node < NN) degFB[dir * NN + node] = degL[tid];
  }
}

// ---- 5. fused GEMM epilogue ----
// out = relu( h@Ws^T + aggF@W^T + aggB@Wt^T + Ws_b + degF*W_b + degB*Wt_b )
__global__ __launch_bounds__(256) void gemm_fused(
    const float* __restrict__ h, const short* __restrict__ aggF,
    const short* __restrict__ aggB, const short* __restrict__ Wbf,
    const float* __restrict__ Wb, const float* __restrict__ Wsb,
    const float* __restrict__ Wtb, const int* __restrict__ degFB,
    float* __restrict__ out) {
  int wave = threadIdx.x >> 6;
  int lane = threadIdx.x & 63;
  int m16  = lane & 15;
  int kq   = lane >> 4;
  int tile_row0 = blockIdx.x * 64 + wave * 16;
  int arow = tile_row0 + m16;
  bool arow_ok = arow < NN;

  bf16x8 afH[4], afF[4], afB[4];
  bf16x8 z;
#pragma unroll
  for (int j = 0; j < 8; j++) z[j] = 0;

  const float* hb = h + (size_t)arow * HIDDEN + kq * 8;
  const short* fb = aggF + (size_t)arow * HIDDEN + kq * 8;
  const short* bb = aggB + (size_t)arow * HIDDEN + kq * 8;
#pragma unroll
  for (int t = 0; t < 4; t++) {
    if (arow_ok) {
      f32x4 lo = *(const f32x4*)(hb + t * 32);
      f32x4 hi = *(const f32x4*)(hb + t * 32 + 4);
      bf16x8 r;
#pragma unroll
      for (int j = 0; j < 4; j++) { r[j] = f2bf(lo[j]); r[j + 4] = f2bf(hi[j]); }
      afH[t] = r;
      afF[t] = *(const bf16x8*)(fb + t * 32);
      afB[t] = *(const bf16x8*)(bb + t * 32);
    } else {
      afH[t] = z; afF[t] = z; afB[t] = z;
    }
  }

  int crow0 = tile_row0 + kq * 4;
  float dF[4], dB[4];
#pragma unroll
  for (int j = 0; j < 4; j++) {
    int r = crow0 + j;
    dF[j] = (r < NN) ? (float)degFB[r] : 0.f;
    dB[j] = (r < NN) ? (float)degFB[NN + r] : 0.f;
  }

#pragma unroll
  for (int nt = 0; nt < 8; nt++) {
    int col = nt * 16 + m16;
    f32x4 acc = {0.f, 0.f, 0.f, 0.f};
    const short* w0 = Wbf + 0 * 16384 + col * HIDDEN + kq * 8;
    const short* w1 = Wbf + 1 * 16384 + col * HIDDEN + kq * 8;
    const short* w2 = Wbf + 2 * 16384 + col * HIDDEN + kq * 8;
#pragma unroll
    for (int t = 0; t < 4; t++)
      acc = __builtin_amdgcn_mfma_f32_16x16x32_bf16(afH[t], *(const bf16x8*)(w0 + t * 32), acc, 0, 0, 0);
#pragma unroll
    for (int t = 0; t < 4; t++)
      acc = __builtin_amdgcn_mfma_f32_16x16x32_bf16(afF[t], *(const bf16x8*)(w1 + t * 32), acc, 0, 0, 0);
#pragma unroll
    for (int t = 0; t < 4; t++)
      acc = __builtin_amdgcn_mfma_f32_16x16x32_bf16(afB[t], *(const bf16x8*)(w2 + t * 32), acc, 0, 0, 0);

    float bW = Wb[col], bS = Wsb[col], bT = Wtb[col];
#pragma unroll
    for (int j = 0; j < 4; j++) {
      int r = crow0 + j;
      if (r < NN) {
        float v = acc[j] + bS + dF[j] * bW + dB[j] * bT;
        out[(size_t)r * HIDDEN + col] = fmaxf(v, 0.f);
      }
    }
  }
}

extern "C" void kernel_launch(void* const* d_in, const int* in_sizes, int n_in,
                              void* d_out, int out_size, void* d_ws, size_t ws_size,
                              hipStream_t stream) {
  const float* h    = (const float*)d_in[0];
  const int*   esrc = (const int*)d_in[1];
  const int*   edst = (const int*)d_in[2];
  const float* Ww   = (const float*)d_in[3];
  const float* Wb   = (const float*)d_in[4];
  const float* Wsw  = (const float*)d_in[5];
  const float* Wsb  = (const float*)d_in[6];
  const float* Wtw  = (const float*)d_in[7];
  const float* Wtb  = (const float*)d_in[8];
  float* out = (float*)d_out;

  char* ws = (char*)d_ws;
  // byte layout
  int*      ghist  = (int*)(ws + 0);            //     6,256
  int*      bstart = (int*)(ws + 6256);         //     6,260
  int*      gcur   = (int*)(ws + 12516);        //     6,256  (ends 18,772)
  unsigned* ELP    = (unsigned*)(ws + 18816);   // 6,400,000  (ends 6,418,816)
  short*    Wbf    = (short*)(ws + 6418816);    //    98,304  (ends 6,517,120)
  short*    aggF   = (short*)(ws + 6517120);    // 25,600,000 (ends 32,117,120)
  short*    aggB   = (short*)(ws + 32117120);   // 25,600,000 (ends 57,717,120)
  int*      degFB  = (int*)(ws + 57717120);     //   800,000  -> total ~58.5 MB

  hipMemsetAsync(ghist, 0, NBUCK * sizeof(int), stream);

  convert_weights<<<192, 256, 0, stream>>>(Wsw, Ww, Wtw, Wbf);
  part_count<<<PBLK, 256, 0, stream>>>(esrc, edst, ghist);
  bucket_scan<<<1, 1024, 0, stream>>>(ghist, bstart, gcur);
  part_scatter<<<PBLK, 256, 0, stream>>>(esrc, edst, gcur, ELP);
  bucket_accum<<<NBUCK, 256, 0, stream>>>(h, ELP, bstart, aggF, aggB, degFB);
  gemm_fused<<<(NN + 63) / 64, 256, 0, stream>>>(
      h, aggF, aggB, Wbf, Wb, Wsb, Wtb, degFB, out);
}

// Round 5
// 349.895 us; speedup vs baseline: 4.2655x; 4.2655x over previous
//
#include <hip/hip_runtime.h>
#include <hip/hip_bf16.h>

#define NN 100000
#define NE 800000
#define HIDDEN 128
#define NED (2 * NE)            // edge-directions: [0,NE)=fwd(by src), [NE,2NE)=bwd(by dst)
#define BKN 128                 // nodes per bucket
#define NBF 782                 // ceil(NN/BKN)
#define NBUCK (2 * NBF)         // 1564
#define CHUNK 8192
#define PBLK ((NED + CHUNK - 1) / CHUNK)   // 196

typedef __attribute__((ext_vector_type(8))) short bf16x8;
typedef __attribute__((ext_vector_type(4))) short bf16x4;
typedef __attribute__((ext_vector_type(4))) float f32x4;

__device__ __forceinline__ short f2bf(float f) {
  union { float f; unsigned u; } x; x.f = f;
  unsigned r = x.u + 0x7fffu + ((x.u >> 16) & 1u);   // RNE
  return (short)(r >> 16);
}
__device__ __forceinline__ float bf2f(short s) {
  union { unsigned u; float f; } x;
  x.u = ((unsigned)(unsigned short)s) << 16;
  return x.f;
}

// ---- weights fp32 -> bf16 (order: [0]=Ws_w, [1]=W_w, [2]=Wt_w) ----
__global__ __launch_bounds__(256) void convert_weights(
    const float* __restrict__ m0, const float* __restrict__ m1,
    const float* __restrict__ m2, short* __restrict__ out) {
  int i = blockIdx.x * 256 + threadIdx.x;   // [0, 3*16384)
  int m = i >> 14, j = i & 16383;
  const float* s = (m == 0) ? m0 : (m == 1) ? m1 : m2;
  out[i] = f2bf(s[j]);
}

// ---- h fp32 -> bf16 (vectorized; NN*HIDDEN = 12.8M, /4 = 3.2M threads exact) ----
__global__ __launch_bounds__(256) void convert_h(
    const float* __restrict__ h, short* __restrict__ h_bf) {
  int i = blockIdx.x * 256 + threadIdx.x;
  f32x4 v = *(const f32x4*)(h + (size_t)i * 4);
  bf16x4 o;
#pragma unroll
  for (int j = 0; j < 4; j++) o[j] = f2bf(v[j]);
  *(bf16x4*)(h_bf + (size_t)i * 4) = o;
}

// ---- 1. global bucket histogram (LDS-aggregated) ----
__global__ __launch_bounds__(256) void part_count(
    const int* __restrict__ esrc, const int* __restrict__ edst,
    int* __restrict__ ghist) {
  __shared__ int lh[NBUCK];
  int tid = threadIdx.x;
  for (int i = tid; i < NBUCK; i += 256) lh[i] = 0;
  __syncthreads();
  int base = blockIdx.x * CHUNK;
  int nit = min(CHUNK, NED - base);
  for (int k = tid; k < nit; k += 256) {
    int ed = base + k;
    int b;
    if (ed < NE) b = esrc[ed] >> 7;
    else b = NBF + (edst[ed - NE] >> 7);
    atomicAdd(&lh[b], 1);
  }
  __syncthreads();
  for (int i = tid; i < NBUCK; i += 256) {
    int c = lh[i];
    if (c) atomicAdd(ghist + i, c);
  }
}

// ---- 2. exclusive scan over ghist[NBUCK] -> bstart (bounds) + gcur (cursors) ----
__global__ __launch_bounds__(1024) void bucket_scan(
    const int* __restrict__ ghist, int* __restrict__ bstart,
    int* __restrict__ gcur) {
  __shared__ int lds[1024];
  __shared__ int carry;
  int tid = threadIdx.x;
  if (tid == 0) carry = 0;
  __syncthreads();
  for (int t = 0; t < 2; t++) {
    int i = t * 1024 + tid;
    int v = (i < NBUCK) ? ghist[i] : 0;
    lds[tid] = v;
    __syncthreads();
    for (int off = 1; off < 1024; off <<= 1) {
      int x = lds[tid];
      int add = (tid >= off) ? lds[tid - off] : 0;
      __syncthreads();
      lds[tid] = x + add;
      __syncthreads();
    }
    int excl = lds[tid] - v + carry;
    if (i < NBUCK) { bstart[i] = excl; gcur[i] = excl; }
    int tot = lds[1023];
    __syncthreads();
    if (tid == 0) carry += tot;
    __syncthreads();
  }
  if (tid == 0) bstart[NBUCK] = carry;   // == NED
}

// ---- 3. radix partition: scatter through LDS, write coalesced runs to ELP ----
// ELP item: (tgt_local<<17) | nbr   (tgt_local<128 -> 7 bits; nbr<100000 -> 17 bits)
__global__ __launch_bounds__(256) void part_scatter(
    const int* __restrict__ esrc, const int* __restrict__ edst,
    int* __restrict__ gcur, unsigned* __restrict__ ELP) {
  __shared__ int lh[NBUCK];
  __shared__ int loff[NBUCK];     // block-local exclusive offsets (kept intact)
  __shared__ int lcur[NBUCK];     // mutable scatter cursors
  __shared__ int gbase[NBUCK];    // claimed global run starts
  __shared__ int psum[256];
  __shared__ unsigned buf[CHUNK]; // 32 KB staging
  int tid = threadIdx.x;
  for (int i = tid; i < NBUCK; i += 256) lh[i] = 0;
  __syncthreads();
  int base = blockIdx.x * CHUNK;
  int nit = min(CHUNK, NED - base);
  // pass 1: local count
  for (int k = tid; k < nit; k += 256) {
    int ed = base + k;
    int b;
    if (ed < NE) b = esrc[ed] >> 7;
    else b = NBF + (edst[ed - NE] >> 7);
    atomicAdd(&lh[b], 1);
  }
  __syncthreads();
  // local exclusive scan (7 buckets per thread; 7*256=1792 >= NBUCK)
  int s = 0;
  int lo0 = tid * 7, hi0 = min(NBUCK, tid * 7 + 7);
  for (int j = lo0; j < hi0; j++) s += lh[j];
  psum[tid] = s;
  __syncthreads();
  for (int off = 1; off < 256; off <<= 1) {
    int x = psum[tid];
    int add = (tid >= off) ? psum[tid - off] : 0;
    __syncthreads();
    psum[tid] = x + add;
    __syncthreads();
  }
  int run = psum[tid] - s;
  for (int j = lo0; j < hi0; j++) { loff[j] = run; lcur[j] = run; run += lh[j]; }
  __syncthreads();
  // claim global runs (one returning atomic per non-empty bucket)
  for (int b = tid; b < NBUCK; b += 256) {
    int c = lh[b];
    if (c) gbase[b] = atomicAdd(gcur + b, c);
  }
  __syncthreads();
  // pass 2: scatter into LDS staging
  for (int k = tid; k < nit; k += 256) {
    int ed = base + k;
    int b, tl, nbr;
    if (ed < NE) { int tg = esrc[ed]; nbr = edst[ed]; b = tg >> 7; tl = tg & 127; }
    else { int e = ed - NE; int tg = edst[e]; nbr = esrc[e]; b = NBF + (tg >> 7); tl = tg & 127; }
    int slot = atomicAdd(&lcur[b], 1);
    buf[slot] = ((unsigned)tl << 17) | (unsigned)nbr;
  }
  __syncthreads();
  // sweep: consecutive lanes -> consecutive slots -> bucket-contiguous global runs
  for (int i = tid; i < nit; i += 256) {
    int lo = 0, hi = NBUCK - 1;
    while (lo < hi) {                       // rightmost b with loff[b] <= i
      int mid = (lo + hi + 1) >> 1;
      if (loff[mid] <= i) lo = mid; else hi = mid - 1;
    }
    ELP[gbase[lo] + (i - loff[lo])] = buf[i];
  }
}

// ---- 4. per-bucket counting-sort + register-accumulated gather ----
// Block owns 128 node rows of one direction. Sort bucket items by local node in
// LDS, then half-wave per node: one bf16x4 vector load per item, fp32 reg accum,
// coalesced 256B agg-row writes. No global RMW, no LDS atomics in hot loop.
__global__ __launch_bounds__(256) void bucket_gather(
    const short* __restrict__ h_bf, const unsigned* __restrict__ ELP,
    const int* __restrict__ bstart,
    short* __restrict__ aggF, short* __restrict__ aggB,
    int* __restrict__ degFB) {
  __shared__ int sorted[2048];   // bucket mean 1024, sigma 32 -> 2048 is 32 sigma
  __shared__ int cnt[BKN];
  __shared__ int pfx[BKN];
  __shared__ int cur[BKN];
  int tid = threadIdx.x;
  int blk = blockIdx.x;
  int s = bstart[blk], e = bstart[blk + 1], n = e - s;
  if (tid < BKN) cnt[tid] = 0;
  __syncthreads();
  for (int k = tid; k < n; k += 256) atomicAdd(&cnt[ELP[s + k] >> 17], 1);
  __syncthreads();
  // inclusive scan of cnt -> pfx
  int v = (tid < BKN) ? cnt[tid] : 0;
  if (tid < BKN) pfx[tid] = v;
  __syncthreads();
  for (int off = 1; off < BKN; off <<= 1) {
    int add = (tid < BKN && tid >= off) ? pfx[tid - off] : 0;
    __syncthreads();
    if (tid < BKN) pfx[tid] += add;
    __syncthreads();
  }
  if (tid < BKN) cur[tid] = pfx[tid] - cnt[tid];   // exclusive start
  __syncthreads();
  // scatter into sorted-by-node LDS array (store nbr only)
  for (int k = tid; k < n; k += 256) {
    unsigned pv = ELP[s + k];
    int slot = atomicAdd(&cur[pv >> 17], 1);
    sorted[slot] = (int)(pv & 0x1FFFFu);
  }
  __syncthreads();
  // gather: half-wave (32 lanes) per node, 4 fp32 accumulators per lane
  int dir = blk >= NBF;
  int node0 = (dir ? blk - NBF : blk) * BKN;
  short* agg = dir ? aggB : aggF;
  int hw = tid >> 5, q = tid & 31;
  for (int t = 0; t < 16; t++) {
    int nd = hw * 16 + t;
    int b = pfx[nd];
    int a = b - cnt[nd];
    float a0 = 0.f, a1 = 0.f, a2 = 0.f, a3 = 0.f;
    if (a < b) {
      int nbr = sorted[a];
      for (int j = a + 1; j < b; j++) {
        int nxt = sorted[j];                              // prefetch index
        bf16x4 vv = *(const bf16x4*)(h_bf + (size_t)nbr * HIDDEN + q * 4);
        a0 += bf2f(vv[0]); a1 += bf2f(vv[1]); a2 += bf2f(vv[2]); a3 += bf2f(vv[3]);
        nbr = nxt;
      }
      bf16x4 vv = *(const bf16x4*)(h_bf + (size_t)nbr * HIDDEN + q * 4);
      a0 += bf2f(vv[0]); a1 += bf2f(vv[1]); a2 += bf2f(vv[2]); a3 += bf2f(vv[3]);
    }
    int node = node0 + nd;
    if (node < NN) {
      bf16x4 o;
      o[0] = f2bf(a0); o[1] = f2bf(a1); o[2] = f2bf(a2); o[3] = f2bf(a3);
      *(bf16x4*)(agg + (size_t)node * HIDDEN + q * 4) = o;
    }
  }
  if (tid < BKN) {
    int node = node0 + tid;
    if (node < NN) degFB[dir * NN + node] = cnt[tid];
  }
}

// ---- 5. fused GEMM epilogue (all A-matrices bf16 now) ----
// out = relu( h@Ws^T + aggF@W^T + aggB@Wt^T + Ws_b + degF*W_b + degB*Wt_b )
__global__ __launch_bounds__(256) void gemm_fused(
    const short* __restrict__ h_bf, const short* __restrict__ aggF,
    const short* __restrict__ aggB, const short* __restrict__ Wbf,
    const float* __restrict__ Wb, const float* __restrict__ Wsb,
    const float* __restrict__ Wtb, const int* __restrict__ degFB,
    float* __restrict__ out) {
  int wave = threadIdx.x >> 6;
  int lane = threadIdx.x & 63;
  int m16  = lane & 15;
  int kq   = lane >> 4;
  int tile_row0 = blockIdx.x * 64 + wave * 16;
  int arow = tile_row0 + m16;
  bool arow_ok = arow < NN;

  bf16x8 afH[4], afF[4], afB[4];
  bf16x8 z;
#pragma unroll
  for (int j = 0; j < 8; j++) z[j] = 0;

  const short* hb = h_bf + (size_t)arow * HIDDEN + kq * 8;
  const short* fb = aggF + (size_t)arow * HIDDEN + kq * 8;
  const short* bb = aggB + (size_t)arow * HIDDEN + kq * 8;
#pragma unroll
  for (int t = 0; t < 4; t++) {
    if (arow_ok) {
      afH[t] = *(const bf16x8*)(hb + t * 32);
      afF[t] = *(const bf16x8*)(fb + t * 32);
      afB[t] = *(const bf16x8*)(bb + t * 32);
    } else {
      afH[t] = z; afF[t] = z; afB[t] = z;
    }
  }

  int crow0 = tile_row0 + kq * 4;
  float dF[4], dB[4];
#pragma unroll
  for (int j = 0; j < 4; j++) {
    int r = crow0 + j;
    dF[j] = (r < NN) ? (float)degFB[r] : 0.f;
    dB[j] = (r < NN) ? (float)degFB[NN + r] : 0.f;
  }

#pragma unroll
  for (int nt = 0; nt < 8; nt++) {
    int col = nt * 16 + m16;
    f32x4 acc = {0.f, 0.f, 0.f, 0.f};
    const short* w0 = Wbf + 0 * 16384 + col * HIDDEN + kq * 8;
    const short* w1 = Wbf + 1 * 16384 + col * HIDDEN + kq * 8;
    const short* w2 = Wbf + 2 * 16384 + col * HIDDEN + kq * 8;
#pragma unroll
    for (int t = 0; t < 4; t++)
      acc = __builtin_amdgcn_mfma_f32_16x16x32_bf16(afH[t], *(const bf16x8*)(w0 + t * 32), acc, 0, 0, 0);
#pragma unroll
    for (int t = 0; t < 4; t++)
      acc = __builtin_amdgcn_mfma_f32_16x16x32_bf16(afF[t], *(const bf16x8*)(w1 + t * 32), acc, 0, 0, 0);
#pragma unroll
    for (int t = 0; t < 4; t++)
      acc = __builtin_amdgcn_mfma_f32_16x16x32_bf16(afB[t], *(const bf16x8*)(w2 + t * 32), acc, 0, 0, 0);

    float bW = Wb[col], bS = Wsb[col], bT = Wtb[col];
#pragma unroll
    for (int j = 0; j < 4; j++) {
      int r = crow0 + j;
      if (r < NN) {
        float v = acc[j] + bS + dF[j] * bW + dB[j] * bT;
        out[(size_t)r * HIDDEN + col] = fmaxf(v, 0.f);
      }
    }
  }
}

extern "C" void kernel_launch(void* const* d_in, const int* in_sizes, int n_in,
                              void* d_out, int out_size, void* d_ws, size_t ws_size,
                              hipStream_t stream) {
  const float* h    = (const float*)d_in[0];
  const int*   esrc = (const int*)d_in[1];
  const int*   edst = (const int*)d_in[2];
  const float* Ww   = (const float*)d_in[3];
  const float* Wb   = (const float*)d_in[4];
  const float* Wsw  = (const float*)d_in[5];
  const float* Wsb  = (const float*)d_in[6];
  const float* Wtw  = (const float*)d_in[7];
  const float* Wtb  = (const float*)d_in[8];
  float* out = (float*)d_out;

  char* ws = (char*)d_ws;
  // byte layout
  int*      ghist  = (int*)(ws + 0);             //     6,256
  int*      bstart = (int*)(ws + 6272);          //     6,260
  int*      gcur   = (int*)(ws + 12544);         //     6,256  (ends 18,800)
  unsigned* ELP    = (unsigned*)(ws + 18816);    // 6,400,000  (ends 6,418,816)
  short*    Wbf    = (short*)(ws + 6418816);     //    98,304  (ends 6,517,120)
  short*    h_bf   = (short*)(ws + 6517120);     // 25,600,000 (ends 32,117,120)
  short*    aggF   = (short*)(ws + 32117120);    // 25,600,000 (ends 57,717,120)
  short*    aggB   = (short*)(ws + 57717120);    // 25,600,000 (ends 83,317,120)
  int*      degFB  = (int*)(ws + 83317120);      //   800,000  -> total ~84.1 MB

  hipMemsetAsync(ghist, 0, NBUCK * sizeof(int), stream);

  convert_weights<<<192, 256, 0, stream>>>(Wsw, Ww, Wtw, Wbf);
  convert_h<<<12500, 256, 0, stream>>>(h, h_bf);
  part_count<<<PBLK, 256, 0, stream>>>(esrc, edst, ghist);
  bucket_scan<<<1, 1024, 0, stream>>>(ghist, bstart, gcur);
  part_scatter<<<PBLK, 256, 0, stream>>>(esrc, edst, gcur, ELP);
  bucket_gather<<<NBUCK, 256, 0, stream>>>(h_bf, ELP, bstart, aggF, aggB, degFB);
  gemm_fused<<<(NN + 63) / 64, 256, 0, stream>>>(
      h_bf, aggF, aggB, Wbf, Wb, Wsb, Wtb, degFB, out);
}

// Round 6
// 320.797 us; speedup vs baseline: 4.6524x; 1.0907x over previous
//
#include <hip/hip_runtime.h>
#include <hip/hip_bf16.h>

#define NN 100000
#define NE 800000
#define HIDDEN 128
#define NED (2 * NE)            // edge-directions: [0,NE)=fwd(by src), [NE,2NE)=bwd(by dst)
#define BKN 128                 // nodes per bucket
#define NBF 782                 // ceil(NN/BKN)
#define NBUCK (2 * NBF)         // 1564
#define CHUNK 8192
#define PBLK ((NED + CHUNK - 1) / CHUNK)   // 196

typedef __attribute__((ext_vector_type(8))) short bf16x8;
typedef __attribute__((ext_vector_type(4))) short bf16x4;
typedef __attribute__((ext_vector_type(4))) float f32x4;

__device__ __forceinline__ short f2bf(float f) {
  union { float f; unsigned u; } x; x.f = f;
  unsigned r = x.u + 0x7fffu + ((x.u >> 16) & 1u);   // RNE
  return (short)(r >> 16);
}
__device__ __forceinline__ float bf2f(short s) {
  union { unsigned u; float f; } x;
  x.u = ((unsigned)(unsigned short)s) << 16;
  return x.f;
}

// ---- weights fp32 -> bf16 (order: [0]=Ws_w, [1]=W_w, [2]=Wt_w) ----
__global__ __launch_bounds__(256) void convert_weights(
    const float* __restrict__ m0, const float* __restrict__ m1,
    const float* __restrict__ m2, short* __restrict__ out) {
  int i = blockIdx.x * 256 + threadIdx.x;   // [0, 3*16384)
  int m = i >> 14, j = i & 16383;
  const float* s = (m == 0) ? m0 : (m == 1) ? m1 : m2;
  out[i] = f2bf(s[j]);
}

// ---- h fp32 -> bf16 (vectorized; NN*HIDDEN = 12.8M, /4 = 3.2M threads exact) ----
__global__ __launch_bounds__(256) void convert_h(
    const float* __restrict__ h, short* __restrict__ h_bf) {
  int i = blockIdx.x * 256 + threadIdx.x;
  f32x4 v = *(const f32x4*)(h + (size_t)i * 4);
  bf16x4 o;
#pragma unroll
  for (int j = 0; j < 4; j++) o[j] = f2bf(v[j]);
  *(bf16x4*)(h_bf + (size_t)i * 4) = o;
}

// ---- 1. global bucket histogram (LDS-aggregated) ----
__global__ __launch_bounds__(256) void part_count(
    const int* __restrict__ esrc, const int* __restrict__ edst,
    int* __restrict__ ghist) {
  __shared__ int lh[NBUCK];
  int tid = threadIdx.x;
  for (int i = tid; i < NBUCK; i += 256) lh[i] = 0;
  __syncthreads();
  int base = blockIdx.x * CHUNK;
  int nit = min(CHUNK, NED - base);
  for (int k = tid; k < nit; k += 256) {
    int ed = base + k;
    int b;
    if (ed < NE) b = esrc[ed] >> 7;
    else b = NBF + (edst[ed - NE] >> 7);
    atomicAdd(&lh[b], 1);
  }
  __syncthreads();
  for (int i = tid; i < NBUCK; i += 256) {
    int c = lh[i];
    if (c) atomicAdd(ghist + i, c);
  }
}

// ---- 2. exclusive scan over ghist[NBUCK] -> bstart (bounds) + gcur (cursors) ----
__global__ __launch_bounds__(1024) void bucket_scan(
    const int* __restrict__ ghist, int* __restrict__ bstart,
    int* __restrict__ gcur) {
  __shared__ int lds[1024];
  __shared__ int carry;
  int tid = threadIdx.x;
  if (tid == 0) carry = 0;
  __syncthreads();
  for (int t = 0; t < 2; t++) {
    int i = t * 1024 + tid;
    int v = (i < NBUCK) ? ghist[i] : 0;
    lds[tid] = v;
    __syncthreads();
    for (int off = 1; off < 1024; off <<= 1) {
      int x = lds[tid];
      int add = (tid >= off) ? lds[tid - off] : 0;
      __syncthreads();
      lds[tid] = x + add;
      __syncthreads();
    }
    int excl = lds[tid] - v + carry;
    if (i < NBUCK) { bstart[i] = excl; gcur[i] = excl; }
    int tot = lds[1023];
    __syncthreads();
    if (tid == 0) carry += tot;
    __syncthreads();
  }
  if (tid == 0) bstart[NBUCK] = carry;   // == NED
}

// ---- 3. radix partition: scatter through LDS, write coalesced runs to ELP ----
// ELP item: (tgt_local<<17) | nbr   (tgt_local<128 -> 7 bits; nbr<100000 -> 17 bits)
__global__ __launch_bounds__(256) void part_scatter(
    const int* __restrict__ esrc, const int* __restrict__ edst,
    int* __restrict__ gcur, unsigned* __restrict__ ELP) {
  __shared__ int lh[NBUCK];
  __shared__ int loff[NBUCK];     // block-local exclusive offsets (kept intact)
  __shared__ int lcur[NBUCK];     // mutable scatter cursors
  __shared__ int gbase[NBUCK];    // claimed global run starts
  __shared__ int psum[256];
  __shared__ unsigned buf[CHUNK]; // 32 KB staging
  int tid = threadIdx.x;
  for (int i = tid; i < NBUCK; i += 256) lh[i] = 0;
  __syncthreads();
  int base = blockIdx.x * CHUNK;
  int nit = min(CHUNK, NED - base);
  // pass 1: local count
  for (int k = tid; k < nit; k += 256) {
    int ed = base + k;
    int b;
    if (ed < NE) b = esrc[ed] >> 7;
    else b = NBF + (edst[ed - NE] >> 7);
    atomicAdd(&lh[b], 1);
  }
  __syncthreads();
  // local exclusive scan (7 buckets per thread; 7*256=1792 >= NBUCK)
  int s = 0;
  int lo0 = tid * 7, hi0 = min(NBUCK, tid * 7 + 7);
  for (int j = lo0; j < hi0; j++) s += lh[j];
  psum[tid] = s;
  __syncthreads();
  for (int off = 1; off < 256; off <<= 1) {
    int x = psum[tid];
    int add = (tid >= off) ? psum[tid - off] : 0;
    __syncthreads();
    psum[tid] = x + add;
    __syncthreads();
  }
  int run = psum[tid] - s;
  for (int j = lo0; j < hi0; j++) { loff[j] = run; lcur[j] = run; run += lh[j]; }
  __syncthreads();
  // claim global runs (one returning atomic per non-empty bucket)
  for (int b = tid; b < NBUCK; b += 256) {
    int c = lh[b];
    if (c) gbase[b] = atomicAdd(gcur + b, c);
  }
  __syncthreads();
  // pass 2: scatter into LDS staging
  for (int k = tid; k < nit; k += 256) {
    int ed = base + k;
    int b, tl, nbr;
    if (ed < NE) { int tg = esrc[ed]; nbr = edst[ed]; b = tg >> 7; tl = tg & 127; }
    else { int e = ed - NE; int tg = edst[e]; nbr = esrc[e]; b = NBF + (tg >> 7); tl = tg & 127; }
    int slot = atomicAdd(&lcur[b], 1);
    buf[slot] = ((unsigned)tl << 17) | (unsigned)nbr;
  }
  __syncthreads();
  // sweep: consecutive lanes -> consecutive slots -> bucket-contiguous global runs
  for (int i = tid; i < nit; i += 256) {
    int lo = 0, hi = NBUCK - 1;
    while (lo < hi) {                       // rightmost b with loff[b] <= i
      int mid = (lo + hi + 1) >> 1;
      if (loff[mid] <= i) lo = mid; else hi = mid - 1;
    }
    ELP[gbase[lo] + (i - loff[lo])] = buf[i];
  }
}

// ---- 4. per-bucket counting-sort + register-accumulated gather ----
__global__ __launch_bounds__(256) void bucket_gather(
    const short* __restrict__ h_bf, const unsigned* __restrict__ ELP,
    const int* __restrict__ bstart,
    short* __restrict__ aggF, short* __restrict__ aggB,
    int* __restrict__ degFB) {
  __shared__ int sorted[2048];   // bucket mean 1024, sigma 32 -> 2048 is 32 sigma
  __shared__ int cnt[BKN];
  __shared__ int pfx[BKN];
  __shared__ int cur[BKN];
  int tid = threadIdx.x;
  int blk = blockIdx.x;
  int s = bstart[blk], e = bstart[blk + 1], n = e - s;
  if (tid < BKN) cnt[tid] = 0;
  __syncthreads();
  for (int k = tid; k < n; k += 256) atomicAdd(&cnt[ELP[s + k] >> 17], 1);
  __syncthreads();
  // inclusive scan of cnt -> pfx
  int v = (tid < BKN) ? cnt[tid] : 0;
  if (tid < BKN) pfx[tid] = v;
  __syncthreads();
  for (int off = 1; off < BKN; off <<= 1) {
    int add = (tid < BKN && tid >= off) ? pfx[tid - off] : 0;
    __syncthreads();
    if (tid < BKN) pfx[tid] += add;
    __syncthreads();
  }
  if (tid < BKN) cur[tid] = pfx[tid] - cnt[tid];   // exclusive start
  __syncthreads();
  // scatter into sorted-by-node LDS array (store nbr only)
  for (int k = tid; k < n; k += 256) {
    unsigned pv = ELP[s + k];
    int slot = atomicAdd(&cur[pv >> 17], 1);
    sorted[slot] = (int)(pv & 0x1FFFFu);
  }
  __syncthreads();
  // gather: half-wave (32 lanes) per node, 4 fp32 accumulators per lane
  int dir = blk >= NBF;
  int node0 = (dir ? blk - NBF : blk) * BKN;
  short* agg = dir ? aggB : aggF;
  int hw = tid >> 5, q = tid & 31;
  for (int t = 0; t < 16; t++) {
    int nd = hw * 16 + t;
    int b = pfx[nd];
    int a = b - cnt[nd];
    float a0 = 0.f, a1 = 0.f, a2 = 0.f, a3 = 0.f;
    if (a < b) {
      int nbr = sorted[a];
      for (int j = a + 1; j < b; j++) {
        int nxt = sorted[j];                              // prefetch index
        bf16x4 vv = *(const bf16x4*)(h_bf + (size_t)nbr * HIDDEN + q * 4);
        a0 += bf2f(vv[0]); a1 += bf2f(vv[1]); a2 += bf2f(vv[2]); a3 += bf2f(vv[3]);
        nbr = nxt;
      }
      bf16x4 vv = *(const bf16x4*)(h_bf + (size_t)nbr * HIDDEN + q * 4);
      a0 += bf2f(vv[0]); a1 += bf2f(vv[1]); a2 += bf2f(vv[2]); a3 += bf2f(vv[3]);
    }
    int node = node0 + nd;
    if (node < NN) {
      bf16x4 o;
      o[0] = f2bf(a0); o[1] = f2bf(a1); o[2] = f2bf(a2); o[3] = f2bf(a3);
      *(bf16x4*)(agg + (size_t)node * HIDDEN + q * 4) = o;
    }
  }
  if (tid < BKN) {
    int node = node0 + tid;
    if (node < NN) degFB[dir * NN + node] = cnt[tid];
  }
}

// ---- 5. fused GEMM epilogue, K-outer / N-inner, acc-resident ----
// out = relu( h@Ws^T + aggF@W^T + aggB@Wt^T + Ws_b + degF*W_b + degB*Wt_b )
// Per wave: 32 rows (2 row-groups share every weight fragment), all 8 col-tiles'
// accumulators live (acc in AGPRs). Each A-fragment loaded once, feeds 8
// independent MFMAs (no serial acc chain). Block = 4 waves = 128 rows.
__global__ __launch_bounds__(256, 4) void gemm_fused(
    const short* __restrict__ h_bf, const short* __restrict__ aggF,
    const short* __restrict__ aggB, const short* __restrict__ Wbf,
    const float* __restrict__ Wb, const float* __restrict__ Wsb,
    const float* __restrict__ Wtb, const int* __restrict__ degFB,
    float* __restrict__ out) {
  int wave = threadIdx.x >> 6;
  int lane = threadIdx.x & 63;
  int m16  = lane & 15;
  int kq   = lane >> 4;
  int row_blk = blockIdx.x * 128 + wave * 32;
  int r0 = row_blk + m16;          // row-group 0 A-row for this lane
  int r1 = row_blk + 16 + m16;     // row-group 1
  bool ok0 = r0 < NN, ok1 = r1 < NN;

  bf16x8 z;
#pragma unroll
  for (int j = 0; j < 8; j++) z[j] = 0;

  f32x4 acc0[8], acc1[8];
#pragma unroll
  for (int nt = 0; nt < 8; nt++) {
    acc0[nt] = (f32x4){0.f, 0.f, 0.f, 0.f};
    acc1[nt] = (f32x4){0.f, 0.f, 0.f, 0.f};
  }

  const short* mats[3] = { h_bf, aggF, aggB };
#pragma unroll
  for (int i = 0; i < 3; i++) {
    const short* a0 = mats[i] + (size_t)r0 * HIDDEN + kq * 8;
    const short* a1 = mats[i] + (size_t)r1 * HIDDEN + kq * 8;
    const short* wm = Wbf + i * 16384 + m16 * HIDDEN + kq * 8;
#pragma unroll
    for (int t = 0; t < 4; t++) {
      bf16x8 af0 = ok0 ? *(const bf16x8*)(a0 + t * 32) : z;
      bf16x8 af1 = ok1 ? *(const bf16x8*)(a1 + t * 32) : z;
#pragma unroll
      for (int nt = 0; nt < 8; nt++) {
        bf16x8 wf = *(const bf16x8*)(wm + nt * 16 * HIDDEN + t * 32);
        acc0[nt] = __builtin_amdgcn_mfma_f32_16x16x32_bf16(af0, wf, acc0[nt], 0, 0, 0);
        acc1[nt] = __builtin_amdgcn_mfma_f32_16x16x32_bf16(af1, wf, acc1[nt], 0, 0, 0);
      }
    }
  }

  // epilogue: C/D mapping col=lane&15, row=kq*4+j
  int cr0 = row_blk + kq * 4;
  int cr1 = row_blk + 16 + kq * 4;
  float dF0[4], dB0[4], dF1[4], dB1[4];
#pragma unroll
  for (int j = 0; j < 4; j++) {
    int ra = cr0 + j, rb = cr1 + j;
    dF0[j] = (ra < NN) ? (float)degFB[ra] : 0.f;
    dB0[j] = (ra < NN) ? (float)degFB[NN + ra] : 0.f;
    dF1[j] = (rb < NN) ? (float)degFB[rb] : 0.f;
    dB1[j] = (rb < NN) ? (float)degFB[NN + rb] : 0.f;
  }
#pragma unroll
  for (int nt = 0; nt < 8; nt++) {
    int col = nt * 16 + m16;
    float bW = Wb[col], bS = Wsb[col], bT = Wtb[col];
#pragma unroll
    for (int j = 0; j < 4; j++) {
      int ra = cr0 + j;
      if (ra < NN) {
        float v = acc0[nt][j] + bS + dF0[j] * bW + dB0[j] * bT;
        out[(size_t)ra * HIDDEN + col] = fmaxf(v, 0.f);
      }
      int rb = cr1 + j;
      if (rb < NN) {
        float v = acc1[nt][j] + bS + dF1[j] * bW + dB1[j] * bT;
        out[(size_t)rb * HIDDEN + col] = fmaxf(v, 0.f);
      }
    }
  }
}

extern "C" void kernel_launch(void* const* d_in, const int* in_sizes, int n_in,
                              void* d_out, int out_size, void* d_ws, size_t ws_size,
                              hipStream_t stream) {
  const float* h    = (const float*)d_in[0];
  const int*   esrc = (const int*)d_in[1];
  const int*   edst = (const int*)d_in[2];
  const float* Ww   = (const float*)d_in[3];
  const float* Wb   = (const float*)d_in[4];
  const float* Wsw  = (const float*)d_in[5];
  const float* Wsb  = (const float*)d_in[6];
  const float* Wtw  = (const float*)d_in[7];
  const float* Wtb  = (const float*)d_in[8];
  float* out = (float*)d_out;

  char* ws = (char*)d_ws;
  // byte layout
  int*      ghist  = (int*)(ws + 0);             //     6,256
  int*      bstart = (int*)(ws + 6272);          //     6,260
  int*      gcur   = (int*)(ws + 12544);         //     6,256  (ends 18,800)
  unsigned* ELP    = (unsigned*)(ws + 18816);    // 6,400,000  (ends 6,418,816)
  short*    Wbf    = (short*)(ws + 6418816);     //    98,304  (ends 6,517,120)
  short*    h_bf   = (short*)(ws + 6517120);     // 25,600,000 (ends 32,117,120)
  short*    aggF   = (short*)(ws + 32117120);    // 25,600,000 (ends 57,717,120)
  short*    aggB   = (short*)(ws + 57717120);    // 25,600,000 (ends 83,317,120)
  int*      degFB  = (int*)(ws + 83317120);      //   800,000  -> total ~84.1 MB

  hipMemsetAsync(ghist, 0, NBUCK * sizeof(int), stream);

  convert_weights<<<192, 256, 0, stream>>>(Wsw, Ww, Wtw, Wbf);
  convert_h<<<12500, 256, 0, stream>>>(h, h_bf);
  part_count<<<PBLK, 256, 0, stream>>>(esrc, edst, ghist);
  bucket_scan<<<1, 1024, 0, stream>>>(ghist, bstart, gcur);
  part_scatter<<<PBLK, 256, 0, stream>>>(esrc, edst, gcur, ELP);
  bucket_gather<<<NBUCK, 256, 0, stream>>>(h_bf, ELP, bstart, aggF, aggB, degFB);
  gemm_fused<<<(NN + 127) / 128, 256, 0, stream>>>(
      h_bf, aggF, aggB, Wbf, Wb, Wsb, Wtb, degFB, out);
}

// Round 8
// 282.666 us; speedup vs baseline: 5.2800x; 1.1349x over previous
//
#include <hip/hip_runtime.h>
#include <hip/hip_bf16.h>

#define NN 100000
#define NE 800000
#define HIDDEN 128
#define NED (2 * NE)            // edge-directions: [0,NE)=fwd(by src), [NE,2NE)=bwd(by dst)
#define BKN 128                 // nodes per bucket
#define NBF 782                 // ceil(NN/BKN)
#define NBUCK (2 * NBF)         // 1564
#define CHUNK 8192
#define PBLK ((NED + CHUNK - 1) / CHUNK)   // 196
#define NTILES 3125             // 100000 / 32 exact

typedef __attribute__((ext_vector_type(8))) short bf16x8;
typedef __attribute__((ext_vector_type(4))) short bf16x4;
typedef __attribute__((ext_vector_type(4))) float f32x4;

__device__ __forceinline__ short f2bf(float f) {
  union { float f; unsigned u; } x; x.f = f;
  unsigned r = x.u + 0x7fffu + ((x.u >> 16) & 1u);   // RNE
  return (short)(r >> 16);
}
__device__ __forceinline__ float bf2f(short s) {
  union { unsigned u; float f; } x;
  x.u = ((unsigned)(unsigned short)s) << 16;
  return x.f;
}

// ---- weights fp32 -> bf16 (order: [0]=Ws_w, [1]=W_w, [2]=Wt_w) ----
__global__ __launch_bounds__(256) void convert_weights(
    const float* __restrict__ m0, const float* __restrict__ m1,
    const float* __restrict__ m2, short* __restrict__ out) {
  int i = blockIdx.x * 256 + threadIdx.x;   // [0, 3*16384)
  int m = i >> 14, j = i & 16383;
  const float* s = (m == 0) ? m0 : (m == 1) ? m1 : m2;
  out[i] = f2bf(s[j]);
}

// ---- h fp32 -> bf16 (vectorized; NN*HIDDEN = 12.8M, /4 = 3.2M threads exact) ----
__global__ __launch_bounds__(256) void convert_h(
    const float* __restrict__ h, short* __restrict__ h_bf) {
  int i = blockIdx.x * 256 + threadIdx.x;
  f32x4 v = *(const f32x4*)(h + (size_t)i * 4);
  bf16x4 o;
#pragma unroll
  for (int j = 0; j < 4; j++) o[j] = f2bf(v[j]);
  *(bf16x4*)(h_bf + (size_t)i * 4) = o;
}

// ---- 1. global bucket histogram (LDS-aggregated) ----
__global__ __launch_bounds__(256) void part_count(
    const int* __restrict__ esrc, const int* __restrict__ edst,
    int* __restrict__ ghist) {
  __shared__ int lh[NBUCK];
  int tid = threadIdx.x;
  for (int i = tid; i < NBUCK; i += 256) lh[i] = 0;
  __syncthreads();
  int base = blockIdx.x * CHUNK;
  int nit = min(CHUNK, NED - base);
  for (int k = tid; k < nit; k += 256) {
    int ed = base + k;
    int b;
    if (ed < NE) b = esrc[ed] >> 7;
    else b = NBF + (edst[ed - NE] >> 7);
    atomicAdd(&lh[b], 1);
  }
  __syncthreads();
  for (int i = tid; i < NBUCK; i += 256) {
    int c = lh[i];
    if (c) atomicAdd(ghist + i, c);
  }
}

// ---- 2. exclusive scan over ghist[NBUCK] -> bstart (bounds) + gcur (cursors) ----
__global__ __launch_bounds__(1024) void bucket_scan(
    const int* __restrict__ ghist, int* __restrict__ bstart,
    int* __restrict__ gcur) {
  __shared__ int lds[1024];
  __shared__ int carry;
  int tid = threadIdx.x;
  if (tid == 0) carry = 0;
  __syncthreads();
  for (int t = 0; t < 2; t++) {
    int i = t * 1024 + tid;
    int v = (i < NBUCK) ? ghist[i] : 0;
    lds[tid] = v;
    __syncthreads();
    for (int off = 1; off < 1024; off <<= 1) {
      int x = lds[tid];
      int add = (tid >= off) ? lds[tid - off] : 0;
      __syncthreads();
      lds[tid] = x + add;
      __syncthreads();
    }
    int excl = lds[tid] - v + carry;
    if (i < NBUCK) { bstart[i] = excl; gcur[i] = excl; }
    int tot = lds[1023];
    __syncthreads();
    if (tid == 0) carry += tot;
    __syncthreads();
  }
  if (tid == 0) bstart[NBUCK] = carry;   // == NED
}

// ---- 3. radix partition: scatter through LDS, write coalesced runs to ELP ----
// ELP item: (tgt_local<<17) | nbr   (tgt_local<128 -> 7 bits; nbr<100000 -> 17 bits)
__global__ __launch_bounds__(256) void part_scatter(
    const int* __restrict__ esrc, const int* __restrict__ edst,
    int* __restrict__ gcur, unsigned* __restrict__ ELP) {
  __shared__ int lh[NBUCK];
  __shared__ int loff[NBUCK];     // block-local exclusive offsets (kept intact)
  __shared__ int lcur[NBUCK];     // mutable scatter cursors
  __shared__ int gbase[NBUCK];    // claimed global run starts
  __shared__ int psum[256];
  __shared__ unsigned buf[CHUNK]; // 32 KB staging
  int tid = threadIdx.x;
  for (int i = tid; i < NBUCK; i += 256) lh[i] = 0;
  __syncthreads();
  int base = blockIdx.x * CHUNK;
  int nit = min(CHUNK, NED - base);
  // pass 1: local count
  for (int k = tid; k < nit; k += 256) {
    int ed = base + k;
    int b;
    if (ed < NE) b = esrc[ed] >> 7;
    else b = NBF + (edst[ed - NE] >> 7);
    atomicAdd(&lh[b], 1);
  }
  __syncthreads();
  // local exclusive scan (7 buckets per thread; 7*256=1792 >= NBUCK)
  int s = 0;
  int lo0 = tid * 7, hi0 = min(NBUCK, tid * 7 + 7);
  for (int j = lo0; j < hi0; j++) s += lh[j];
  psum[tid] = s;
  __syncthreads();
  for (int off = 1; off < 256; off <<= 1) {
    int x = psum[tid];
    int add = (tid >= off) ? psum[tid - off] : 0;
    __syncthreads();
    psum[tid] = x + add;
    __syncthreads();
  }
  int run = psum[tid] - s;
  for (int j = lo0; j < hi0; j++) { loff[j] = run; lcur[j] = run; run += lh[j]; }
  __syncthreads();
  // claim global runs (one returning atomic per non-empty bucket)
  for (int b = tid; b < NBUCK; b += 256) {
    int c = lh[b];
    if (c) gbase[b] = atomicAdd(gcur + b, c);
  }
  __syncthreads();
  // pass 2: scatter into LDS staging
  for (int k = tid; k < nit; k += 256) {
    int ed = base + k;
    int b, tl, nbr;
    if (ed < NE) { int tg = esrc[ed]; nbr = edst[ed]; b = tg >> 7; tl = tg & 127; }
    else { int e = ed - NE; int tg = edst[e]; nbr = esrc[e]; b = NBF + (tg >> 7); tl = tg & 127; }
    int slot = atomicAdd(&lcur[b], 1);
    buf[slot] = ((unsigned)tl << 17) | (unsigned)nbr;
  }
  __syncthreads();
  // sweep: consecutive lanes -> consecutive slots -> bucket-contiguous global runs
  for (int i = tid; i < nit; i += 256) {
    int lo = 0, hi = NBUCK - 1;
    while (lo < hi) {                       // rightmost b with loff[b] <= i
      int mid = (lo + hi + 1) >> 1;
      if (loff[mid] <= i) lo = mid; else hi = mid - 1;
    }
    ELP[gbase[lo] + (i - loff[lo])] = buf[i];
  }
}

// ---- 4. per-bucket counting-sort + register-accumulated gather ----
__global__ __launch_bounds__(256) void bucket_gather(
    const short* __restrict__ h_bf, const unsigned* __restrict__ ELP,
    const int* __restrict__ bstart,
    short* __restrict__ aggF, short* __restrict__ aggB,
    int* __restrict__ degFB) {
  __shared__ int sorted[2048];   // bucket mean 1024, sigma 32 -> 2048 is 32 sigma
  __shared__ int cnt[BKN];
  __shared__ int pfx[BKN];
  __shared__ int cur[BKN];
  int tid = threadIdx.x;
  int blk = blockIdx.x;
  int s = bstart[blk], e = bstart[blk + 1], n = e - s;
  if (tid < BKN) cnt[tid] = 0;
  __syncthreads();
  for (int k = tid; k < n; k += 256) atomicAdd(&cnt[ELP[s + k] >> 17], 1);
  __syncthreads();
  // inclusive scan of cnt -> pfx
  int v = (tid < BKN) ? cnt[tid] : 0;
  if (tid < BKN) pfx[tid] = v;
  __syncthreads();
  for (int off = 1; off < BKN; off <<= 1) {
    int add = (tid < BKN && tid >= off) ? pfx[tid - off] : 0;
    __syncthreads();
    if (tid < BKN) pfx[tid] += add;
    __syncthreads();
  }
  if (tid < BKN) cur[tid] = pfx[tid] - cnt[tid];   // exclusive start
  __syncthreads();
  // scatter into sorted-by-node LDS array (store nbr only)
  for (int k = tid; k < n; k += 256) {
    unsigned pv = ELP[s + k];
    int slot = atomicAdd(&cur[pv >> 17], 1);
    sorted[slot] = (int)(pv & 0x1FFFFu);
  }
  __syncthreads();
  // gather: half-wave (32 lanes) per node, 4 fp32 accumulators per lane
  int dir = blk >= NBF;
  int node0 = (dir ? blk - NBF : blk) * BKN;
  short* agg = dir ? aggB : aggF;
  int hw = tid >> 5, q = tid & 31;
  for (int t = 0; t < 16; t++) {
    int nd = hw * 16 + t;
    int b = pfx[nd];
    int a = b - cnt[nd];
    float a0 = 0.f, a1 = 0.f, a2 = 0.f, a3 = 0.f;
    if (a < b) {
      int nbr = sorted[a];
      for (int j = a + 1; j < b; j++) {
        int nxt = sorted[j];                              // prefetch index
        bf16x4 vv = *(const bf16x4*)(h_bf + (size_t)nbr * HIDDEN + q * 4);
        a0 += bf2f(vv[0]); a1 += bf2f(vv[1]); a2 += bf2f(vv[2]); a3 += bf2f(vv[3]);
        nbr = nxt;
      }
      bf16x4 vv = *(const bf16x4*)(h_bf + (size_t)nbr * HIDDEN + q * 4);
      a0 += bf2f(vv[0]); a1 += bf2f(vv[1]); a2 += bf2f(vv[2]); a3 += bf2f(vv[3]);
    }
    int node = node0 + nd;
    if (node < NN) {
      bf16x4 o;
      o[0] = f2bf(a0); o[1] = f2bf(a1); o[2] = f2bf(a2); o[3] = f2bf(a3);
      *(bf16x4*)(agg + (size_t)node * HIDDEN + q * 4) = o;
    }
  }
  if (tid < BKN) {
    int node = node0 + tid;
    if (node < NN) degFB[dir * NN + node] = cnt[tid];
  }
}

// ---- 5. fused GEMM: register-persistent weights, LDS-streamed activations ----
// out = relu( h@Ws^T + aggF@W^T + aggB@Wt^T + Ws_b + degF*W_b + degB*Wt_b )
// Block = 512 thr = 8 waves; wave w owns cols [w*16, w*16+16) with its 12
// weight fragments register-persistent. Grid-stride over 32-row tiles: stage
// 3x32x128 bf16 activations into LDS (coalesced, +8-short row pad), all 8
// waves share them (8x reuse). mfma(wf, af) computes W·act^T so each lane's 4
// acc elements are 4 consecutive out cols -> one f32x4 store per row-group.
// Staging: 1536 16B-chunks = 512 threads x 3 matrices (row=tid>>4, kc=tid&15).
__global__ __launch_bounds__(512, 4) void gemm_fused(
    const short* __restrict__ h_bf, const short* __restrict__ aggF,
    const short* __restrict__ aggB, const short* __restrict__ Wbf,
    const float* __restrict__ Wb, const float* __restrict__ Wsb,
    const float* __restrict__ Wtb, const int* __restrict__ degFB,
    float* __restrict__ out) {
  __shared__ short At[3 * 32 * 136];   // 26112 B, rows padded 128->136 shorts
  int tid = threadIdx.x;
  int lane = tid & 63;
  int m16 = lane & 15;
  int kq  = lane >> 4;
  int col0 = (tid >> 6) * 16;          // wave's 16-col tile

  // register-persistent weight fragments (one-time scattered loads)
  bf16x8 wf[3][4];
#pragma unroll
  for (int i = 0; i < 3; i++)
#pragma unroll
    for (int t = 0; t < 4; t++)
      wf[i][t] = *(const bf16x8*)(Wbf + i * 16384 + (col0 + m16) * 128 + t * 32 + kq * 8);

  // per-lane bias vectors for out cols col0+kq*4 .. +4 (hoisted)
  f32x4 bW = *(const f32x4*)(Wb  + col0 + kq * 4);
  f32x4 bS = *(const f32x4*)(Wsb + col0 + kq * 4);
  f32x4 bT = *(const f32x4*)(Wtb + col0 + kq * 4);

  // staging map: thread stages chunk (row=tid>>4, kc=tid&15) of each matrix
  int srow = tid >> 4, skc = tid & 15;
  const short* mats[3] = { h_bf, aggF, aggB };
  const short* gbs[3];
  short* lps[3];
#pragma unroll
  for (int k = 0; k < 3; k++) {
    gbs[k] = mats[k] + srow * 128 + skc * 8;
    lps[k] = At + k * 4352 + srow * 136 + skc * 8;
  }

  int tile = blockIdx.x;
  bf16x8 ld[3];
#pragma unroll
  for (int k = 0; k < 3; k++)
    ld[k] = *(const bf16x8*)(gbs[k] + (size_t)tile * 4096);

  while (tile < NTILES) {
    int row0 = tile * 32;
    __syncthreads();                 // previous compute done reading LDS
#pragma unroll
    for (int k = 0; k < 3; k++) *(bf16x8*)lps[k] = ld[k];
    __syncthreads();
    int ntile = tile + gridDim.x;
    if (ntile < NTILES) {            // prefetch next tile during compute
#pragma unroll
      for (int k = 0; k < 3; k++)
        ld[k] = *(const bf16x8*)(gbs[k] + (size_t)ntile * 4096);
    }
#pragma unroll
    for (int g = 0; g < 2; g++) {
      f32x4 acc = {0.f, 0.f, 0.f, 0.f};
      const short* lb = At + (g * 16 + m16) * 136 + kq * 8;
#pragma unroll
      for (int i = 0; i < 3; i++)
#pragma unroll
        for (int t = 0; t < 4; t++) {
          bf16x8 af = *(const bf16x8*)(lb + i * 4352 + t * 32);
          acc = __builtin_amdgcn_mfma_f32_16x16x32_bf16(wf[i][t], af, acc, 0, 0, 0);
        }
      // D lane reg j: out row = row0+g*16+m16, out col = col0+kq*4+j
      int r = row0 + g * 16 + m16;
      float dF = (float)degFB[r];
      float dB = (float)degFB[NN + r];
      f32x4 v;
#pragma unroll
      for (int j = 0; j < 4; j++)
        v[j] = fmaxf(acc[j] + bS[j] + dF * bW[j] + dB * bT[j], 0.f);
      *(f32x4*)(out + (size_t)r * HIDDEN + col0 + kq * 4) = v;
    }
    tile = ntile;
  }
}

extern "C" void kernel_launch(void* const* d_in, const int* in_sizes, int n_in,
                              void* d_out, int out_size, void* d_ws, size_t ws_size,
                              hipStream_t stream) {
  const float* h    = (const float*)d_in[0];
  const int*   esrc = (const int*)d_in[1];
  const int*   edst = (const int*)d_in[2];
  const float* Ww   = (const float*)d_in[3];
  const float* Wb   = (const float*)d_in[4];
  const float* Wsw  = (const float*)d_in[5];
  const float* Wsb  = (const float*)d_in[6];
  const float* Wtw  = (const float*)d_in[7];
  const float* Wtb  = (const float*)d_in[8];
  float* out = (float*)d_out;

  char* ws = (char*)d_ws;
  // byte layout
  int*      ghist  = (int*)(ws + 0);             //     6,256
  int*      bstart = (int*)(ws + 6272);          //     6,260
  int*      gcur   = (int*)(ws + 12544);         //     6,256  (ends 18,800)
  unsigned* ELP    = (unsigned*)(ws + 18816);    // 6,400,000  (ends 6,418,816)
  short*    Wbf    = (short*)(ws + 6418816);     //    98,304  (ends 6,517,120)
  short*    h_bf   = (short*)(ws + 6517120);     // 25,600,000 (ends 32,117,120)
  short*    aggF   = (short*)(ws + 32117120);    // 25,600,000 (ends 57,717,120)
  short*    aggB   = (short*)(ws + 57717120);    // 25,600,000 (ends 83,317,120)
  int*      degFB  = (int*)(ws + 83317120);      //   800,000  -> total ~84.1 MB

  hipMemsetAsync(ghist, 0, NBUCK * sizeof(int), stream);

  convert_weights<<<192, 256, 0, stream>>>(Wsw, Ww, Wtw, Wbf);
  convert_h<<<12500, 256, 0, stream>>>(h, h_bf);
  part_count<<<PBLK, 256, 0, stream>>>(esrc, edst, ghist);
  bucket_scan<<<1, 1024, 0, stream>>>(ghist, bstart, gcur);
  part_scatter<<<PBLK, 256, 0, stream>>>(esrc, edst, gcur, ELP);
  bucket_gather<<<NBUCK, 256, 0, stream>>>(h_bf, ELP, bstart, aggF, aggB, degFB);
  gemm_fused<<<1024, 512, 0, stream>>>(
      h_bf, aggF, aggB, Wbf, Wb, Wsb, Wtb, degFB, out);
}